// Round 8
// baseline (673.083 us; speedup 1.0000x reference)
//
#include <hip/hip_runtime.h>

#define BATCH 4
#define SEQ   2048
#define EMBD  2048
#define NHEAD 16
#define HEADD 128

#define GM (BATCH*SEQ)   // 8192
#define GN EMBD          // 2048
#define GK EMBD          // 2048

typedef __attribute__((ext_vector_type(8))) short short8;
typedef __attribute__((ext_vector_type(4))) short s16x4;
typedef __attribute__((ext_vector_type(4))) float f32x4;

static __device__ __forceinline__ short f2bf(float f) {
  unsigned u = __builtin_bit_cast(unsigned, f);
  unsigned r = (u + 0x7fffu + ((u >> 16) & 1u)) >> 16;
  return (short)r;
}

static __device__ __forceinline__ unsigned cvt_pk_bf16(float lo, float hi) {
  unsigned r;
  asm("v_cvt_pk_bf16_f32 %0, %1, %2" : "=v"(r) : "v"(lo), "v"(hi));
  return r;
}

// async global->LDS, 16B per lane. LDS dest is wave-uniform base + lane*16.
static __device__ __forceinline__ void glds16(const short* g, short* l) {
  __builtin_amdgcn_global_load_lds(
      (const __attribute__((address_space(1))) unsigned int*)g,
      (__attribute__((address_space(3))) unsigned int*)l, 16, 0, 0);
}

// ---------------------------------------------------------------------------
// fused fp32 -> bf16 conversion: y in 0..3 -> W matrices, y in 4..7 -> x
// quarters (NE == 4*NW exactly).
// ---------------------------------------------------------------------------
#define NWELT (EMBD*EMBD)   // 4,194,304

__global__ __launch_bounds__(256) void cvt_all(
    const float* __restrict__ x,
    const float* __restrict__ w0, const float* __restrict__ w1,
    const float* __restrict__ w2, const float* __restrict__ w3,
    short* __restrict__ xb,
    short* __restrict__ o0, short* __restrict__ o1,
    short* __restrict__ o2, short* __restrict__ o3)
{
  const int y = blockIdx.y;
  const float* src;
  short* dst;
  if (y < 4) {
    src = y == 0 ? w0 : y == 1 ? w1 : y == 2 ? w2 : w3;
    dst = y == 0 ? o0 : y == 1 ? o1 : y == 2 ? o2 : o3;
  } else {
    src = x  + (size_t)(y - 4) * NWELT;
    dst = xb + (size_t)(y - 4) * NWELT;
  }
  int i = (blockIdx.x * 256 + threadIdx.x) * 8;
  float4 a = *(const float4*)&src[i];
  float4 b = *(const float4*)&src[i + 4];
  short8 o;
  o[0] = f2bf(a.x); o[1] = f2bf(a.y); o[2] = f2bf(a.z); o[3] = f2bf(a.w);
  o[4] = f2bf(b.x); o[5] = f2bf(b.y); o[6] = f2bf(b.z); o[7] = f2bf(b.w);
  *(short8*)&dst[i] = o;
}

// ---------------------------------------------------------------------------
// GEMM core: 8-phase 256x256 template, v2 (rebalanced phase reads).
// Quadrant order Q00->Q01->Q10->Q11 with per-phase ds_reads {4,4,8,8}:
//   P1: read bfA(4);           stage A-h1(kt+1);  MFMA Q00 (afA x bfA)
//   P2: read bfB(4);                              MFMA Q01 (afA x bfB)
//   P3: read afB(8);           stage B-h0(kt+2);  MFMA Q10 (afB x bfA)
//   P4: stage B-h1+A-h0(kt+2); vmcnt(6); barrier;
//       READ-AHEAD afA(kt+1) from the next buffer (resident after vmcnt);
//       MFMA Q11 (afB x bfB) -- no lgkm dependency, overlaps the DS reads.
// Region-hazard audit: B reads end P2 < B-h0 stage P3; afB read P3 < A-h0
// stage P4; read-ahead targets buffer d^1 whose kt+1 halves are complete
// (vmcnt(6) drains exactly the 8 kt+1 glds) and staging at P4 goes to
// different halves of d^1. afA registers: last use P2, re-read P4.
// ---------------------------------------------------------------------------
#define NKT (GK / 64)   // 32 K-tiles

template<bool F32OUT>
static __device__ __forceinline__ void gemm_body(
    const short* __restrict__ A, const short* __restrict__ W,
    const float* __restrict__ bias, void* __restrict__ Cout,
    short SH[2][2][2][128 * 64])
{
  const int tid  = threadIdx.x;
  const int lane = tid & 63;
  const int wv   = tid >> 6;          // 0..7
  const int quad = lane >> 4;
  const int l15  = lane & 15;
  const int rsw  = l15 & 7;           // row&7 for all fragment rows

  // XCD swizzle: 256 blocks (8 n x 32 m), bijective since 256 % 8 == 0.
  const int bid = blockIdx.x;
  const int swz = (bid & 7) * 32 + (bid >> 3);
  const int n0 = (swz & 7) * 256;
  const int m0 = (swz >> 3) * 256;

  const int hA = wv >> 2;             // this wave's A half (M-half)
  const int hB = (wv & 3) >> 1;       // this wave's B half (N-half)
  const int bl = (wv & 1) * 64;       // local n base within B half

  // staging: thread stages granules j*512+tid; LDS is linear in granule id,
  // global column-granule = slot ^ (row&7)  (inverse of the read swizzle)
  int grow[2], gcol[2];
#pragma unroll
  for (int j = 0; j < 2; ++j) {
    int gi = j * 512 + tid;
    int row = gi >> 3, slot = gi & 7;
    grow[j] = row;
    gcol[j] = (slot ^ (row & 7)) * 8;
  }

#define STG(mat_, src_, rb_, kt_, h_) do {                                   \
    short* ld_ = &SH[(kt_) & 1][mat_][h_][0];                                \
    _Pragma("unroll")                                                        \
    for (int j = 0; j < 2; ++j)                                              \
      glds16(&src_[(size_t)((rb_) + (h_) * 128 + grow[j]) * GK +             \
                   (kt_) * 64 + gcol[j]],                                    \
             &ld_[(j * 512 + wv * 64) * 8]);                                 \
  } while (0)

  // fragment reads: row = subtile row, slot = (ks*4+quad) ^ (row&7)
#define ARDB(base_, mi_, ks_) (*(const short8*)&base_[                       \
    (((mi_) * 16 + l15) * 8 + (((ks_) * 4 + quad) ^ rsw)) * 8])
#define BRD(ni_, ks_) (*(const short8*)&Bbase[                               \
    ((bl + (ni_) * 16 + l15) * 8 + (((ks_) * 4 + quad) ^ rsw)) * 8])

  const f32x4 zerov = {0.f, 0.f, 0.f, 0.f};
  f32x4 acc[8][4];
#pragma unroll
  for (int mi = 0; mi < 8; ++mi)
#pragma unroll
    for (int ni = 0; ni < 4; ++ni) acc[mi][ni] = zerov;

  short8 afA[4][2];   // persists across iterations (read-ahead at P4)

  // prologue: K-tile 0 fully + 3 halves of K-tile 1 (invariant entry state)
  STG(0, A, m0, 0, 0); STG(1, W, n0, 0, 0); STG(1, W, n0, 0, 1);
  STG(0, A, m0, 0, 1);
  STG(1, W, n0, 1, 0); STG(1, W, n0, 1, 1); STG(0, A, m0, 1, 0);
  asm volatile("s_waitcnt vmcnt(6)" ::: "memory");   // K-tile 0 resident
  __builtin_amdgcn_sched_barrier(0);
  __builtin_amdgcn_s_barrier();
  __builtin_amdgcn_sched_barrier(0);
  {  // prologue read of afA(kt=0)
    const short* Abase0 = &SH[0][0][hA][0];
#pragma unroll
    for (int mi = 0; mi < 4; ++mi)
#pragma unroll
      for (int ks = 0; ks < 2; ++ks) afA[mi][ks] = ARDB(Abase0, mi, ks);
  }

  for (int kt = 0; kt < NKT; ++kt) {
    const int d = kt & 1;
    const short* Abase = &SH[d][0][hA][0];
    const short* Bbase = &SH[d][1][hB][0];
    short8 afB[4][2], bfA[2][2], bfB[2][2];

    // ---------------- P1: read bfA(4); stage A-h1(kt+1); Q00 (afA x bfA)
#pragma unroll
    for (int ni = 0; ni < 2; ++ni)
#pragma unroll
      for (int ks = 0; ks < 2; ++ks) bfA[ni][ks] = BRD(ni, ks);
    if (kt + 1 < NKT) STG(0, A, m0, kt + 1, 1);
    __builtin_amdgcn_sched_barrier(0);
    __builtin_amdgcn_s_barrier();
    asm volatile("s_waitcnt lgkmcnt(0)" ::: "memory");
    __builtin_amdgcn_sched_barrier(0);
    __builtin_amdgcn_s_setprio(1);
#pragma unroll
    for (int mi = 0; mi < 4; ++mi)
#pragma unroll
      for (int ni = 0; ni < 2; ++ni)
#pragma unroll
        for (int ks = 0; ks < 2; ++ks)
          acc[mi][ni] = __builtin_amdgcn_mfma_f32_16x16x32_bf16(afA[mi][ks], bfA[ni][ks], acc[mi][ni], 0, 0, 0);
    __builtin_amdgcn_s_setprio(0);
    __builtin_amdgcn_sched_barrier(0);
    __builtin_amdgcn_s_barrier();

    // ---------------- P2: read bfB(4); Q01 (afA x bfB)
#pragma unroll
    for (int ni = 0; ni < 2; ++ni)
#pragma unroll
      for (int ks = 0; ks < 2; ++ks) bfB[ni][ks] = BRD(ni + 2, ks);
    __builtin_amdgcn_sched_barrier(0);
    __builtin_amdgcn_s_barrier();
    asm volatile("s_waitcnt lgkmcnt(0)" ::: "memory");
    __builtin_amdgcn_sched_barrier(0);
    __builtin_amdgcn_s_setprio(1);
#pragma unroll
    for (int mi = 0; mi < 4; ++mi)
#pragma unroll
      for (int ni = 0; ni < 2; ++ni)
#pragma unroll
        for (int ks = 0; ks < 2; ++ks)
          acc[mi][ni + 2] = __builtin_amdgcn_mfma_f32_16x16x32_bf16(afA[mi][ks], bfB[ni][ks], acc[mi][ni + 2], 0, 0, 0);
    __builtin_amdgcn_s_setprio(0);
    __builtin_amdgcn_sched_barrier(0);
    __builtin_amdgcn_s_barrier();

    // ---------------- P3: read afB(8); stage B-h0(kt+2); Q10 (afB x bfA)
#pragma unroll
    for (int mi = 0; mi < 4; ++mi)
#pragma unroll
      for (int ks = 0; ks < 2; ++ks) afB[mi][ks] = ARDB(Abase, mi + 4, ks);
    if (kt + 2 < NKT) STG(1, W, n0, kt + 2, 0);
    __builtin_amdgcn_sched_barrier(0);
    __builtin_amdgcn_s_barrier();
    asm volatile("s_waitcnt lgkmcnt(0)" ::: "memory");
    __builtin_amdgcn_sched_barrier(0);
    __builtin_amdgcn_s_setprio(1);
#pragma unroll
    for (int mi = 0; mi < 4; ++mi)
#pragma unroll
      for (int ni = 0; ni < 2; ++ni)
#pragma unroll
        for (int ks = 0; ks < 2; ++ks)
          acc[mi + 4][ni] = __builtin_amdgcn_mfma_f32_16x16x32_bf16(afB[mi][ks], bfA[ni][ks], acc[mi + 4][ni], 0, 0, 0);
    __builtin_amdgcn_s_setprio(0);
    __builtin_amdgcn_sched_barrier(0);
    __builtin_amdgcn_s_barrier();

    // ---------------- P4: stage B-h1+A-h0(kt+2); vmcnt(6); barrier;
    //                  read-ahead afA(kt+1); Q11 (afB x bfB, no lgkm dep)
    if (kt + 2 < NKT) { STG(1, W, n0, kt + 2, 1); STG(0, A, m0, kt + 2, 0); }
    if (kt + 2 < NKT)      asm volatile("s_waitcnt vmcnt(6)" ::: "memory");
    else if (kt + 1 < NKT) asm volatile("s_waitcnt vmcnt(0)" ::: "memory");
    __builtin_amdgcn_sched_barrier(0);
    __builtin_amdgcn_s_barrier();
    __builtin_amdgcn_sched_barrier(0);
    if (kt + 1 < NKT) {
      const short* AbaseN = &SH[d ^ 1][0][hA][0];
#pragma unroll
      for (int mi = 0; mi < 4; ++mi)
#pragma unroll
        for (int ks = 0; ks < 2; ++ks) afA[mi][ks] = ARDB(AbaseN, mi, ks);
    }
    __builtin_amdgcn_s_setprio(1);
#pragma unroll
    for (int mi = 0; mi < 4; ++mi)
#pragma unroll
      for (int ni = 0; ni < 2; ++ni)
#pragma unroll
        for (int ks = 0; ks < 2; ++ks)
          acc[mi + 4][ni + 2] = __builtin_amdgcn_mfma_f32_16x16x32_bf16(afB[mi][ks], bfB[ni][ks], acc[mi + 4][ni + 2], 0, 0, 0);
    __builtin_amdgcn_s_setprio(0);
    __builtin_amdgcn_sched_barrier(0);
    __builtin_amdgcn_s_barrier();
  }
#undef STG
#undef ARDB
#undef BRD

  const int wm0 = hA * 128;
  const int wn0 = (wv & 3) * 64;
#pragma unroll
  for (int mi = 0; mi < 8; ++mi) {
    int mg = m0 + wm0 + mi * 16 + quad * 4;
#pragma unroll
    for (int ni = 0; ni < 4; ++ni) {
      int ng = n0 + wn0 + ni * 16 + l15;
      float bv = bias[ng];
#pragma unroll
      for (int r = 0; r < 4; ++r) {
        float val = acc[mi][ni][r] + bv;
        if (F32OUT)
          ((float*)Cout)[(size_t)(mg + r) * GN + ng] = val;
        else
          ((short*)Cout)[(size_t)(mg + r) * GN + ng] = f2bf(val);
      }
    }
  }
}

// Fused QKV: grid (256, 3); y selects {Wq,bq,q} / {Wk,bk,k} / {Wv,bv,v}.
__global__ __launch_bounds__(512, 2) void gemm_qkv(
    const short* __restrict__ A,
    const short* __restrict__ Wq, const short* __restrict__ Wk,
    const short* __restrict__ Wv,
    const float* __restrict__ bq, const float* __restrict__ bk,
    const float* __restrict__ bv,
    short* __restrict__ q, short* __restrict__ k, short* __restrict__ v)
{
  __shared__ short SH[2][2][2][128 * 64];   // 128 KiB
  const int y = blockIdx.y;
  const short* W = y == 0 ? Wq : y == 1 ? Wk : Wv;
  const float* b = y == 0 ? bq : y == 1 ? bk : bv;
  short*       C = y == 0 ? q  : y == 1 ? k  : v;
  gemm_body<false>(A, W, b, C, SH);
}

__global__ __launch_bounds__(512, 2) void gemm_out(
    const short* __restrict__ A, const short* __restrict__ W,
    const float* __restrict__ bias, float* __restrict__ Cout)
{
  __shared__ short SH[2][2][2][128 * 64];   // 128 KiB
  gemm_body<true>(A, W, bias, Cout, SH);
}

// ---------------------------------------------------------------------------
// V transpose: V[b][s][e] -> Vt[b][e][s], 64x64 tiles.
// ---------------------------------------------------------------------------
__global__ __launch_bounds__(256) void transpose_v(
    const short* __restrict__ V, short* __restrict__ Vt)
{
  __shared__ short T[64][72];
  const int b  = blockIdx.z;
  const int n0 = blockIdx.x * 64;
  const int s0 = blockIdx.y * 64;
#pragma unroll
  for (int rr = 0; rr < 2; ++rr) {
    int c = rr * 256 + threadIdx.x;
    int srow = c >> 3;
    int ncol = (c & 7) << 3;
    *(short8*)&T[srow][ncol] = *(const short8*)&V[((size_t)b * SEQ + s0 + srow) * EMBD + n0 + ncol];
  }
  __syncthreads();
#pragma unroll
  for (int rr = 0; rr < 2; ++rr) {
    int c = rr * 256 + threadIdx.x;
    int nrow = c >> 3;
    int scol = (c & 7) << 3;
    short8 o;
#pragma unroll
    for (int j = 0; j < 8; ++j) o[j] = T[scol + j][nrow];
    *(short8*)&Vt[((size_t)b * EMBD + n0 + nrow) * SEQ + s0 + scol] = o;
  }
}

// ---------------------------------------------------------------------------
// Flash attention (causal), v4b (unchanged from R6/R7: 134.7 us, passed).
// ---------------------------------------------------------------------------
__global__ __launch_bounds__(512, 4) void flash_attn(
    const short* __restrict__ Q, const short* __restrict__ K,
    const short* __restrict__ Vt, short* __restrict__ Ctx)
{
  __shared__ short Ksf[2][64 * 128];   // 32 KB [key][d] swizzled granules
  __shared__ short Vsf[2][128 * 64];   // 32 KB [d][key] swizzled granules
  __shared__ short Ps[8][16 * 64];     // 16 KB per-wave P, XOR-swizzled

  const int bid = blockIdx.x;
  const int grp = ((bid & 7) << 3) | (bid >> 6);  // (b,h) group 0..63
  const int xq  = (bid >> 3) & 7;                 // q-tile pair 0..7
  const int h = grp & 15, b = grp >> 4;

  const int tid = threadIdx.x, lane = tid & 63, wv = tid >> 6;  // wv 0..7
  const int quad = lane >> 4, l15 = lane & 15;

  const size_t bhq    = (size_t)b * SEQ * EMBD + (size_t)h * HEADD;
  const size_t vtbase = ((size_t)b * EMBD + (size_t)h * HEADD) * SEQ;
  const float SL2E = 0.08838834764831845f * 1.4426950408889634f;  // scale*log2e
  const float THRS = 8.0f / SL2E;
  const int NQT = SEQ / 128;  // 16 q-tiles of 128 rows

  int kco[2], koff[2], voff[2];
#pragma unroll
  for (int rr = 0; rr < 2; ++rr) {
    int c = rr * 8 + wv;
    int g = c * 64 + lane;
    kco[rr] = c * 512;
    { int row = g >> 4, col16 = (g & 15) ^ (row & 15);
      koff[rr] = row * EMBD + col16 * 8; }
    { int row = g >> 3, col8 = (g & 7) ^ (row & 7);
      voff[rr] = row * SEQ + col8 * 8; }
  }

#define STAGE(buf, kt_) do {                                                 \
    const short* kb_ = &K[bhq + (size_t)((kt_) * 64) * EMBD];                \
    const short* vb_ = &Vt[vtbase + (size_t)((kt_) * 64)];                   \
    _Pragma("unroll")                                                        \
    for (int rr = 0; rr < 2; ++rr) {                                         \
      glds16(&kb_[koff[rr]], &Ksf[buf][kco[rr]]);                            \
      glds16(&vb_[voff[rr]], &Vsf[buf][kco[rr]]);                            \
    }                                                                        \
  } while (0)

  const f32x4 zerov = {0.f, 0.f, 0.f, 0.f};

  for (int pass = 0; pass < 2; ++pass) {
    const int qt = pass ? (NQT - 1 - xq) : xq;
    const int qg    = qt * 128 + wv * 16 + l15;       // this lane's q-row
    const int rowg0 = qt * 128 + wv * 16 + quad * 4;  // O-accumulator rows
    const int KTMAX = 2 * qt + 1;                     // last key tile

    short8 qf[4];
#pragma unroll
    for (int ks = 0; ks < 4; ++ks)
      qf[ks] = *(const short8*)&Q[bhq + (size_t)qg * EMBD + ks * 32 + quad * 8];

    f32x4 oacc[8];
#pragma unroll
    for (int ni = 0; ni < 8; ++ni) oacc[ni] = zerov;
    float m_s = -INFINITY;
    float l_s = 0.f;

    __syncthreads();         // prev pass LDS reads complete
    __builtin_amdgcn_sched_barrier(0);
    STAGE(0, 0);
    __builtin_amdgcn_sched_barrier(0);

    for (int kt = 0; kt <= KTMAX; ++kt) {
      const int cur = kt & 1;
      __syncthreads();                       // publishes tile kt
      __builtin_amdgcn_sched_barrier(0);
      if (kt < KTMAX) STAGE(cur ^ 1, kt + 1);
      __builtin_amdgcn_sched_barrier(0);

      // S^T = K Q^T  (A = K-frag m=key, B = Q-frag n=q)
      f32x4 sA[4];
#pragma unroll
      for (int ni = 0; ni < 4; ++ni) sA[ni] = zerov;
      __builtin_amdgcn_s_setprio(1);
#pragma unroll
      for (int ks = 0; ks < 4; ++ks)
#pragma unroll
        for (int ni = 0; ni < 4; ++ni) {
          int row = ni * 16 + l15;
          short8 kf = *(const short8*)&Ksf[cur][(row * 16 + ((ks * 4 + quad) ^ (row & 15))) * 8];
          sA[ni] = __builtin_amdgcn_mfma_f32_16x16x32_bf16(kf, qf[ks], sA[ni], 0, 0, 0);
        }
      __builtin_amdgcn_s_setprio(0);
      // sA[ni][r] = S[key = kt*64 + ni*16 + quad*4 + r][q = qg]

      // causal mask: the last two tiles can cross the diagonal
      if (kt >= 2 * qt) {
        const int key00 = kt * 64;
#pragma unroll
        for (int ni = 0; ni < 4; ++ni)
#pragma unroll
          for (int r = 0; r < 4; ++r) {
            int keyg = key00 + ni * 16 + quad * 4 + r;
            if (keyg > qg) sA[ni][r] = -INFINITY;
          }
      }

      // online softmax (row q = qg): in-lane reduce + 2 shfl_xor
      float mv = sA[0][0];
#pragma unroll
      for (int ni = 0; ni < 4; ++ni)
#pragma unroll
        for (int r = 0; r < 4; ++r)
          if (ni | r) mv = fmaxf(mv, sA[ni][r]);
      mv = fmaxf(mv, __shfl_xor(mv, 16, 64));
      mv = fmaxf(mv, __shfl_xor(mv, 32, 64));

      // defer-max: rescale only when max grew by > 8 (log2 domain)
      if (!__all(mv <= m_s + THRS)) {
        float mn = fmaxf(m_s, mv);
        float alpha = exp2f((m_s - mn) * SL2E);
        m_s = mn;
        l_s *= alpha;
        float al[4];
#pragma unroll
        for (int r = 0; r < 4; ++r) al[r] = __shfl(alpha, quad * 4 + r, 16);
#pragma unroll
        for (int ni = 0; ni < 8; ++ni)
#pragma unroll
          for (int r = 0; r < 4; ++r) oacc[ni][r] *= al[r];
      }

      float msl = m_s * SL2E;
      float sum = 0.f;
#pragma unroll
      for (int ni = 0; ni < 4; ++ni)
#pragma unroll
        for (int r = 0; r < 4; ++r) {
          float p = exp2f(sA[ni][r] * SL2E - msl);
          sA[ni][r] = p;
          sum += p;
        }
      sum += __shfl_xor(sum, 16, 64);
      sum += __shfl_xor(sum, 32, 64);
      l_s += sum;

      // P -> per-wave LDS, XOR-swizzled (no pad):
      // write 8B at granule (ni*2+(quad>>1))^(l15&7), half quad&1
#pragma unroll
      for (int ni = 0; ni < 4; ++ni) {
        uint2 pk;
        pk.x = cvt_pk_bf16(sA[ni][0], sA[ni][1]);
        pk.y = cvt_pk_bf16(sA[ni][2], sA[ni][3]);
        int wg = (((ni * 2 + (quad >> 1)) ^ (l15 & 7)) << 3) + ((quad & 1) << 2);
        *(uint2*)&Ps[wv][l15 * 64 + wg] = pk;
      }

      // read b128 at granule (ks*4+quad)^(l15&7)  (same-wave RAW via lgkm)
      short8 pf[2];
#pragma unroll
      for (int ks = 0; ks < 2; ++ks)
        pf[ks] = *(const short8*)&Ps[wv][l15 * 64 + (((ks * 4 + quad) ^ (l15 & 7)) << 3)];

      // O += P V
      __builtin_amdgcn_s_setprio(1);
#pragma unroll
      for (int ni = 0; ni < 8; ++ni)
#pragma unroll
        for (int ks = 0; ks < 2; ++ks) {
          int row = ni * 16 + l15;
          short8 vf = *(const short8*)&Vsf[cur][(row * 8 + ((ks * 4 + quad) ^ (row & 7))) * 8];
          oacc[ni] = __builtin_amdgcn_mfma_f32_16x16x32_bf16(pf[ks], vf, oacc[ni], 0, 0, 0);
        }
      __builtin_amdgcn_s_setprio(0);
      __builtin_amdgcn_sched_barrier(0);  // iteration boundary pin
    }

    // epilogue: O / l -> ctx
    float linv = 1.0f / l_s;
    float iv[4];
#pragma unroll
    for (int r = 0; r < 4; ++r) iv[r] = __shfl(linv, quad * 4 + r, 16);
#pragma unroll
    for (int r = 0; r < 4; ++r)
#pragma unroll
      for (int ni = 0; ni < 8; ++ni)
        Ctx[bhq + (size_t)(rowg0 + r) * EMBD + ni * 16 + l15] = f2bf(oacc[ni][r] * iv[r]);
  }
#undef STAGE
}

// ---------------------------------------------------------------------------
extern "C" void kernel_launch(void* const* d_in, const int* in_sizes, int n_in,
                              void* d_out, int out_size, void* d_ws, size_t ws_size,
                              hipStream_t stream)
{
  const float* x  = (const float*)d_in[0];
  // d_in[1] = attn_mask: exactly causal tril(0/-inf) -> applied analytically
  const float* Wq = (const float*)d_in[2];
  const float* bq = (const float*)d_in[3];
  const float* Wk = (const float*)d_in[4];
  const float* bk = (const float*)d_in[5];
  const float* Wv = (const float*)d_in[6];
  const float* bv = (const float*)d_in[7];
  const float* Wo = (const float*)d_in[8];
  const float* bo = (const float*)d_in[9];
  float* out = (float*)d_out;

  const size_t NE = (size_t)BATCH * SEQ * EMBD;  // 16,777,216
  const size_t NW = (size_t)EMBD * EMBD;         //  4,194,304
  short* xb  = (short*)d_ws;
  short* wqb = xb  + NE;
  short* wkb = wqb + NW;
  short* wvb = wkb + NW;
  short* wob = wvb + NW;
  short* q   = wob + NW;
  short* k   = q   + NE;
  short* v   = k   + NE;
  short* vt  = v   + NE;
  short* ctx = v;   // v dead after transpose; total ws = 192 MiB

  // fused conversions: one launch (x is exactly 4*NW elements)
  cvt_all<<<dim3(NW / (256 * 8), 8), 256, 0, stream>>>(
      x, Wq, Wk, Wv, Wo, xb, wqb, wkb, wvb, wob);

  // fused QKV projection: (256 blocks) x 3
  gemm_qkv<<<dim3(256, 3), 512, 0, stream>>>(
      xb, wqb, wkb, wvb, bq, bk, bv, q, k, v);
  transpose_v<<<dim3(EMBD / 64, SEQ / 64, BATCH), 256, 0, stream>>>(v, vt);
  // 512 blocks, 8 waves each: exactly 2 blocks/CU (80 KB LDS), one round
  flash_attn<<<dim3(512), 512, 0, stream>>>(q, k, vt, ctx);
  gemm_out<<<dim3(256), 512, 0, stream>>>(ctx, wob, bo, out);
}

// Round 9
// 541.810 us; speedup vs baseline: 1.2423x; 1.2423x over previous
//
#include <hip/hip_runtime.h>

#define BATCH 4
#define SEQ   2048
#define EMBD  2048
#define NHEAD 16
#define HEADD 128

#define GM (BATCH*SEQ)   // 8192
#define GN EMBD          // 2048
#define GK EMBD          // 2048

typedef __attribute__((ext_vector_type(8))) short short8;
typedef __attribute__((ext_vector_type(4))) short s16x4;
typedef __attribute__((ext_vector_type(4))) float f32x4;

static __device__ __forceinline__ short f2bf(float f) {
  unsigned u = __builtin_bit_cast(unsigned, f);
  unsigned r = (u + 0x7fffu + ((u >> 16) & 1u)) >> 16;
  return (short)r;
}

static __device__ __forceinline__ unsigned cvt_pk_bf16(float lo, float hi) {
  unsigned r;
  asm("v_cvt_pk_bf16_f32 %0, %1, %2" : "=v"(r) : "v"(lo), "v"(hi));
  return r;
}

// async global->LDS, 16B per lane. LDS dest is wave-uniform base + lane*16.
static __device__ __forceinline__ void glds16(const short* g, short* l) {
  __builtin_amdgcn_global_load_lds(
      (const __attribute__((address_space(1))) unsigned int*)g,
      (__attribute__((address_space(3))) unsigned int*)l, 16, 0, 0);
}

// ---------------------------------------------------------------------------
// fused fp32 -> bf16 conversion: y in 0..3 -> W matrices, y in 4..7 -> x
// quarters (NE == 4*NW exactly).
// ---------------------------------------------------------------------------
#define NWELT (EMBD*EMBD)   // 4,194,304

__global__ __launch_bounds__(256) void cvt_all(
    const float* __restrict__ x,
    const float* __restrict__ w0, const float* __restrict__ w1,
    const float* __restrict__ w2, const float* __restrict__ w3,
    short* __restrict__ xb,
    short* __restrict__ o0, short* __restrict__ o1,
    short* __restrict__ o2, short* __restrict__ o3)
{
  const int y = blockIdx.y;
  const float* src;
  short* dst;
  if (y < 4) {
    src = y == 0 ? w0 : y == 1 ? w1 : y == 2 ? w2 : w3;
    dst = y == 0 ? o0 : y == 1 ? o1 : y == 2 ? o2 : o3;
  } else {
    src = x  + (size_t)(y - 4) * NWELT;
    dst = xb + (size_t)(y - 4) * NWELT;
  }
  int i = (blockIdx.x * 256 + threadIdx.x) * 8;
  float4 a = *(const float4*)&src[i];
  float4 b = *(const float4*)&src[i + 4];
  short8 o;
  o[0] = f2bf(a.x); o[1] = f2bf(a.y); o[2] = f2bf(a.z); o[3] = f2bf(a.w);
  o[4] = f2bf(b.x); o[5] = f2bf(b.y); o[6] = f2bf(b.z); o[7] = f2bf(b.w);
  *(short8*)&dst[i] = o;
}

// ---------------------------------------------------------------------------
// GEMM core: 8-phase 256x256 template -- EXACT R7 choreography (measured
// MfmaUtil 41.4%, 214.6 us for QKV). R8's read-rebalance regressed and is
// reverted. MODE: 0 = bf16 linear out, 1 = f32 linear out,
// 2 = bf16 TRANSPOSED out to Vt[b][e][s] via LDS re-tile (replaces the
// separate transpose_v kernel; SH is dead after the K-loop and the 256x256
// bf16 tile fits it exactly).
// ---------------------------------------------------------------------------
#define NKT (GK / 64)   // 32 K-tiles

template<int MODE>
static __device__ __forceinline__ void gemm_body(
    const short* __restrict__ A, const short* __restrict__ W,
    const float* __restrict__ bias, void* __restrict__ Cout,
    short SH[2][2][2][128 * 64])
{
  const int tid  = threadIdx.x;
  const int lane = tid & 63;
  const int wv   = tid >> 6;          // 0..7
  const int quad = lane >> 4;
  const int l15  = lane & 15;
  const int rsw  = l15 & 7;           // row&7 for all fragment rows

  // XCD swizzle: 256 blocks (8 n x 32 m), bijective since 256 % 8 == 0.
  const int bid = blockIdx.x;
  const int swz = (bid & 7) * 32 + (bid >> 3);
  const int n0 = (swz & 7) * 256;
  const int m0 = (swz >> 3) * 256;

  const int hA = wv >> 2;             // this wave's A half (M-half)
  const int hB = (wv & 3) >> 1;       // this wave's B half (N-half)
  const int bl = (wv & 1) * 64;       // local n base within B half

  // staging: thread stages granules j*512+tid; LDS is linear in granule id,
  // global column-granule = slot ^ (row&7)  (inverse of the read swizzle)
  int grow[2], gcol[2];
#pragma unroll
  for (int j = 0; j < 2; ++j) {
    int gi = j * 512 + tid;
    int row = gi >> 3, slot = gi & 7;
    grow[j] = row;
    gcol[j] = (slot ^ (row & 7)) * 8;
  }

#define STG(mat_, src_, rb_, kt_, h_) do {                                   \
    short* ld_ = &SH[(kt_) & 1][mat_][h_][0];                                \
    _Pragma("unroll")                                                        \
    for (int j = 0; j < 2; ++j)                                              \
      glds16(&src_[(size_t)((rb_) + (h_) * 128 + grow[j]) * GK +             \
                   (kt_) * 64 + gcol[j]],                                    \
             &ld_[(j * 512 + wv * 64) * 8]);                                 \
  } while (0)

  // fragment reads: row = subtile row, slot = (ks*4+quad) ^ (row&7)
#define ARD(mi_, ks_) (*(const short8*)&Abase[                               \
    (((mi_) * 16 + l15) * 8 + (((ks_) * 4 + quad) ^ rsw)) * 8])
#define BRD(ni_, ks_) (*(const short8*)&Bbase[                               \
    ((bl + (ni_) * 16 + l15) * 8 + (((ks_) * 4 + quad) ^ rsw)) * 8])

  const f32x4 zerov = {0.f, 0.f, 0.f, 0.f};
  f32x4 acc[8][4];
#pragma unroll
  for (int mi = 0; mi < 8; ++mi)
#pragma unroll
    for (int ni = 0; ni < 4; ++ni) acc[mi][ni] = zerov;

  // prologue: K-tile 0 fully + 3 halves of K-tile 1 (invariant entry state)
  STG(0, A, m0, 0, 0); STG(1, W, n0, 0, 0); STG(1, W, n0, 0, 1);
  STG(0, A, m0, 0, 1);
  STG(1, W, n0, 1, 0); STG(1, W, n0, 1, 1); STG(0, A, m0, 1, 0);
  asm volatile("s_waitcnt vmcnt(6)" ::: "memory");   // K-tile 0 resident
  __builtin_amdgcn_sched_barrier(0);
  __builtin_amdgcn_s_barrier();

  for (int kt = 0; kt < NKT; ++kt) {
    const int d = kt & 1;
    const short* Abase = &SH[d][0][hA][0];
    const short* Bbase = &SH[d][1][hB][0];
    short8 afA[4][2], afB[4][2], bfA[2][2], bfB[2][2];

    // ---------------- P1: A(m0-3) + B(n0-1); stage A-h1(kt+1); Q00
#pragma unroll
    for (int mi = 0; mi < 4; ++mi)
#pragma unroll
      for (int ks = 0; ks < 2; ++ks) afA[mi][ks] = ARD(mi, ks);
#pragma unroll
    for (int ni = 0; ni < 2; ++ni)
#pragma unroll
      for (int ks = 0; ks < 2; ++ks) bfA[ni][ks] = BRD(ni, ks);
    if (kt + 1 < NKT) STG(0, A, m0, kt + 1, 1);
    __builtin_amdgcn_sched_barrier(0);
    asm volatile("s_waitcnt lgkmcnt(8)" ::: "memory");
    __builtin_amdgcn_s_barrier();
    asm volatile("s_waitcnt lgkmcnt(0)" ::: "memory");
    __builtin_amdgcn_sched_barrier(0);
    __builtin_amdgcn_s_setprio(1);
#pragma unroll
    for (int mi = 0; mi < 4; ++mi)
#pragma unroll
      for (int ni = 0; ni < 2; ++ni)
#pragma unroll
        for (int ks = 0; ks < 2; ++ks)
          acc[mi][ni] = __builtin_amdgcn_mfma_f32_16x16x32_bf16(afA[mi][ks], bfA[ni][ks], acc[mi][ni], 0, 0, 0);
    __builtin_amdgcn_s_setprio(0);
    __builtin_amdgcn_sched_barrier(0);
    __builtin_amdgcn_s_barrier();

    // ---------------- P2: B(n2-3); Q01   (frees B(kt) after this phase)
#pragma unroll
    for (int ni = 0; ni < 2; ++ni)
#pragma unroll
      for (int ks = 0; ks < 2; ++ks) bfB[ni][ks] = BRD(ni + 2, ks);
    __builtin_amdgcn_sched_barrier(0);
    __builtin_amdgcn_s_barrier();
    asm volatile("s_waitcnt lgkmcnt(0)" ::: "memory");
    __builtin_amdgcn_sched_barrier(0);
    __builtin_amdgcn_s_setprio(1);
#pragma unroll
    for (int mi = 0; mi < 4; ++mi)
#pragma unroll
      for (int ni = 0; ni < 2; ++ni)
#pragma unroll
        for (int ks = 0; ks < 2; ++ks)
          acc[mi][ni + 2] = __builtin_amdgcn_mfma_f32_16x16x32_bf16(afA[mi][ks], bfB[ni][ks], acc[mi][ni + 2], 0, 0, 0);
    __builtin_amdgcn_s_setprio(0);
    __builtin_amdgcn_sched_barrier(0);
    __builtin_amdgcn_s_barrier();

    // ---------------- P3: A(m4-7); stage B-h0(kt+2); Q10  (frees A(kt))
#pragma unroll
    for (int mi = 0; mi < 4; ++mi)
#pragma unroll
      for (int ks = 0; ks < 2; ++ks) afB[mi][ks] = ARD(mi + 4, ks);
    if (kt + 2 < NKT) STG(1, W, n0, kt + 2, 0);
    __builtin_amdgcn_sched_barrier(0);
    __builtin_amdgcn_s_barrier();
    asm volatile("s_waitcnt lgkmcnt(0)" ::: "memory");
    __builtin_amdgcn_sched_barrier(0);
    __builtin_amdgcn_s_setprio(1);
#pragma unroll
    for (int mi = 0; mi < 4; ++mi)
#pragma unroll
      for (int ni = 0; ni < 2; ++ni)
#pragma unroll
        for (int ks = 0; ks < 2; ++ks)
          acc[mi + 4][ni] = __builtin_amdgcn_mfma_f32_16x16x32_bf16(afB[mi][ks], bfA[ni][ks], acc[mi + 4][ni], 0, 0, 0);
    __builtin_amdgcn_s_setprio(0);
    __builtin_amdgcn_sched_barrier(0);
    __builtin_amdgcn_s_barrier();

    // ---------------- P4: stage B-h1+A-h0(kt+2); vmcnt(6); Q11
    if (kt + 2 < NKT) { STG(1, W, n0, kt + 2, 1); STG(0, A, m0, kt + 2, 0); }
    if (kt + 2 < NKT)      asm volatile("s_waitcnt vmcnt(6)" ::: "memory");
    else if (kt + 1 < NKT) asm volatile("s_waitcnt vmcnt(0)" ::: "memory");
    __builtin_amdgcn_sched_barrier(0);
    __builtin_amdgcn_s_barrier();
    __builtin_amdgcn_sched_barrier(0);
    __builtin_amdgcn_s_setprio(1);
#pragma unroll
    for (int mi = 0; mi < 4; ++mi)
#pragma unroll
      for (int ni = 0; ni < 2; ++ni)
#pragma unroll
        for (int ks = 0; ks < 2; ++ks)
          acc[mi + 4][ni + 2] = __builtin_amdgcn_mfma_f32_16x16x32_bf16(afB[mi][ks], bfB[ni][ks], acc[mi + 4][ni + 2], 0, 0, 0);
    __builtin_amdgcn_s_setprio(0);
    __builtin_amdgcn_sched_barrier(0);
    __builtin_amdgcn_s_barrier();
  }
#undef STG
#undef ARD
#undef BRD

  const int wm0 = hA * 128;
  const int wn0 = (wv & 3) * 64;

  if (MODE == 2) {
    // V epilogue: stage C^T in SH (XOR-swizzled 8B granules), then stream
    // coalesced rows to Vt[b][e][s]. Tile never spans a batch boundary
    // (m0 multiple of 256, SEQ % 256 == 0).
    short* T = &SH[0][0][0][0];   // [256 rows (n)][256 cols (m)] shorts
#pragma unroll
    for (int mi = 0; mi < 8; ++mi) {
      int mlb = wm0 + mi * 16 + quad * 4;     // local m base, r = 0..3
#pragma unroll
      for (int ni = 0; ni < 4; ++ni) {
        int nl = wn0 + ni * 16 + l15;
        float bv = bias[n0 + nl];
        s16x4 pk;
#pragma unroll
        for (int r = 0; r < 4; ++r) pk[r] = f2bf(acc[mi][ni][r] + bv);
        int gw = (mlb >> 2) ^ ((nl & 7) << 3);  // swizzled 8B granule
        *(s16x4*)&T[nl * 256 + gw * 4] = pk;
      }
    }
    __syncthreads();
    {
      int nl = tid >> 1;                       // output row (e-local)
      size_t vb = ((size_t)(m0 >> 11) * EMBD + n0 + nl) * SEQ + (m0 & 2047);
      short* Vt = (short*)Cout;
#pragma unroll
      for (int j = 0; j < 16; ++j) {
        int c  = (tid & 1) * 16 + j;           // 16B chunk within row
        int cr = c ^ ((nl & 7) << 2);          // unswizzled chunk index
        *(short8*)&Vt[vb + c * 8] = *(const short8*)&T[nl * 256 + cr * 8];
      }
    }
  } else {
#pragma unroll
    for (int mi = 0; mi < 8; ++mi) {
      int mg = m0 + wm0 + mi * 16 + quad * 4;
#pragma unroll
      for (int ni = 0; ni < 4; ++ni) {
        int ng = n0 + wn0 + ni * 16 + l15;
        float bv = bias[ng];
#pragma unroll
        for (int r = 0; r < 4; ++r) {
          float val = acc[mi][ni][r] + bv;
          if (MODE == 1)
            ((float*)Cout)[(size_t)(mg + r) * GN + ng] = val;
          else
            ((short*)Cout)[(size_t)(mg + r) * GN + ng] = f2bf(val);
        }
      }
    }
  }
}

// Fused QKV: grid (256, 3); y selects {Wq,bq,q} / {Wk,bk,k} / {Wv,bv,Vt}.
// y==2 writes V directly TRANSPOSED (replaces transpose_v).
__global__ __launch_bounds__(512, 2) void gemm_qkv(
    const short* __restrict__ A,
    const short* __restrict__ Wq, const short* __restrict__ Wk,
    const short* __restrict__ Wv,
    const float* __restrict__ bq, const float* __restrict__ bk,
    const float* __restrict__ bv,
    short* __restrict__ q, short* __restrict__ k, short* __restrict__ vt)
{
  __shared__ short SH[2][2][2][128 * 64];   // 128 KiB
  const int y = blockIdx.y;
  if (y == 2) {
    gemm_body<2>(A, Wv, bv, vt, SH);
  } else {
    const short* W = y == 0 ? Wq : Wk;
    const float* b = y == 0 ? bq : bk;
    short*       C = y == 0 ? q  : k;
    gemm_body<0>(A, W, b, C, SH);
  }
}

__global__ __launch_bounds__(512, 2) void gemm_out(
    const short* __restrict__ A, const short* __restrict__ W,
    const float* __restrict__ bias, float* __restrict__ Cout)
{
  __shared__ short SH[2][2][2][128 * 64];   // 128 KiB
  gemm_body<1>(A, W, bias, Cout, SH);
}

// ---------------------------------------------------------------------------
// Flash attention (causal), v4b (unchanged from R6/R7: 134.7 us, passed).
// ---------------------------------------------------------------------------
__global__ __launch_bounds__(512, 4) void flash_attn(
    const short* __restrict__ Q, const short* __restrict__ K,
    const short* __restrict__ Vt, short* __restrict__ Ctx)
{
  __shared__ short Ksf[2][64 * 128];   // 32 KB [key][d] swizzled granules
  __shared__ short Vsf[2][128 * 64];   // 32 KB [d][key] swizzled granules
  __shared__ short Ps[8][16 * 64];     // 16 KB per-wave P, XOR-swizzled

  const int bid = blockIdx.x;
  const int grp = ((bid & 7) << 3) | (bid >> 6);  // (b,h) group 0..63
  const int xq  = (bid >> 3) & 7;                 // q-tile pair 0..7
  const int h = grp & 15, b = grp >> 4;

  const int tid = threadIdx.x, lane = tid & 63, wv = tid >> 6;  // wv 0..7
  const int quad = lane >> 4, l15 = lane & 15;

  const size_t bhq    = (size_t)b * SEQ * EMBD + (size_t)h * HEADD;
  const size_t vtbase = ((size_t)b * EMBD + (size_t)h * HEADD) * SEQ;
  const float SL2E = 0.08838834764831845f * 1.4426950408889634f;  // scale*log2e
  const float THRS = 8.0f / SL2E;
  const int NQT = SEQ / 128;  // 16 q-tiles of 128 rows

  int kco[2], koff[2], voff[2];
#pragma unroll
  for (int rr = 0; rr < 2; ++rr) {
    int c = rr * 8 + wv;
    int g = c * 64 + lane;
    kco[rr] = c * 512;
    { int row = g >> 4, col16 = (g & 15) ^ (row & 15);
      koff[rr] = row * EMBD + col16 * 8; }
    { int row = g >> 3, col8 = (g & 7) ^ (row & 7);
      voff[rr] = row * SEQ + col8 * 8; }
  }

#define STAGE(buf, kt_) do {                                                 \
    const short* kb_ = &K[bhq + (size_t)((kt_) * 64) * EMBD];                \
    const short* vb_ = &Vt[vtbase + (size_t)((kt_) * 64)];                   \
    _Pragma("unroll")                                                        \
    for (int rr = 0; rr < 2; ++rr) {                                         \
      glds16(&kb_[koff[rr]], &Ksf[buf][kco[rr]]);                            \
      glds16(&vb_[voff[rr]], &Vsf[buf][kco[rr]]);                            \
    }                                                                        \
  } while (0)

  const f32x4 zerov = {0.f, 0.f, 0.f, 0.f};

  for (int pass = 0; pass < 2; ++pass) {
    const int qt = pass ? (NQT - 1 - xq) : xq;
    const int qg    = qt * 128 + wv * 16 + l15;       // this lane's q-row
    const int rowg0 = qt * 128 + wv * 16 + quad * 4;  // O-accumulator rows
    const int KTMAX = 2 * qt + 1;                     // last key tile

    short8 qf[4];
#pragma unroll
    for (int ks = 0; ks < 4; ++ks)
      qf[ks] = *(const short8*)&Q[bhq + (size_t)qg * EMBD + ks * 32 + quad * 8];

    f32x4 oacc[8];
#pragma unroll
    for (int ni = 0; ni < 8; ++ni) oacc[ni] = zerov;
    float m_s = -INFINITY;
    float l_s = 0.f;

    __syncthreads();         // prev pass LDS reads complete
    __builtin_amdgcn_sched_barrier(0);
    STAGE(0, 0);
    __builtin_amdgcn_sched_barrier(0);

    for (int kt = 0; kt <= KTMAX; ++kt) {
      const int cur = kt & 1;
      __syncthreads();                       // publishes tile kt
      __builtin_amdgcn_sched_barrier(0);
      if (kt < KTMAX) STAGE(cur ^ 1, kt + 1);
      __builtin_amdgcn_sched_barrier(0);

      // S^T = K Q^T  (A = K-frag m=key, B = Q-frag n=q)
      f32x4 sA[4];
#pragma unroll
      for (int ni = 0; ni < 4; ++ni) sA[ni] = zerov;
      __builtin_amdgcn_s_setprio(1);
#pragma unroll
      for (int ks = 0; ks < 4; ++ks)
#pragma unroll
        for (int ni = 0; ni < 4; ++ni) {
          int row = ni * 16 + l15;
          short8 kf = *(const short8*)&Ksf[cur][(row * 16 + ((ks * 4 + quad) ^ (row & 15))) * 8];
          sA[ni] = __builtin_amdgcn_mfma_f32_16x16x32_bf16(kf, qf[ks], sA[ni], 0, 0, 0);
        }
      __builtin_amdgcn_s_setprio(0);
      // sA[ni][r] = S[key = kt*64 + ni*16 + quad*4 + r][q = qg]

      // causal mask: the last two tiles can cross the diagonal
      if (kt >= 2 * qt) {
        const int key00 = kt * 64;
#pragma unroll
        for (int ni = 0; ni < 4; ++ni)
#pragma unroll
          for (int r = 0; r < 4; ++r) {
            int keyg = key00 + ni * 16 + quad * 4 + r;
            if (keyg > qg) sA[ni][r] = -INFINITY;
          }
      }

      // online softmax (row q = qg): in-lane reduce + 2 shfl_xor
      float mv = sA[0][0];
#pragma unroll
      for (int ni = 0; ni < 4; ++ni)
#pragma unroll
        for (int r = 0; r < 4; ++r)
          if (ni | r) mv = fmaxf(mv, sA[ni][r]);
      mv = fmaxf(mv, __shfl_xor(mv, 16, 64));
      mv = fmaxf(mv, __shfl_xor(mv, 32, 64));

      // defer-max: rescale only when max grew by > 8 (log2 domain)
      if (!__all(mv <= m_s + THRS)) {
        float mn = fmaxf(m_s, mv);
        float alpha = exp2f((m_s - mn) * SL2E);
        m_s = mn;
        l_s *= alpha;
        float al[4];
#pragma unroll
        for (int r = 0; r < 4; ++r) al[r] = __shfl(alpha, quad * 4 + r, 16);
#pragma unroll
        for (int ni = 0; ni < 8; ++ni)
#pragma unroll
          for (int r = 0; r < 4; ++r) oacc[ni][r] *= al[r];
      }

      float msl = m_s * SL2E;
      float sum = 0.f;
#pragma unroll
      for (int ni = 0; ni < 4; ++ni)
#pragma unroll
        for (int r = 0; r < 4; ++r) {
          float p = exp2f(sA[ni][r] * SL2E - msl);
          sA[ni][r] = p;
          sum += p;
        }
      sum += __shfl_xor(sum, 16, 64);
      sum += __shfl_xor(sum, 32, 64);
      l_s += sum;

      // P -> per-wave LDS, XOR-swizzled (no pad):
      // write 8B at granule (ni*2+(quad>>1))^(l15&7), half quad&1
#pragma unroll
      for (int ni = 0; ni < 4; ++ni) {
        uint2 pk;
        pk.x = cvt_pk_bf16(sA[ni][0], sA[ni][1]);
        pk.y = cvt_pk_bf16(sA[ni][2], sA[ni][3]);
        int wg = (((ni * 2 + (quad >> 1)) ^ (l15 & 7)) << 3) + ((quad & 1) << 2);
        *(uint2*)&Ps[wv][l15 * 64 + wg] = pk;
      }

      // read b128 at granule (ks*4+quad)^(l15&7)  (same-wave RAW via lgkm)
      short8 pf[2];
#pragma unroll
      for (int ks = 0; ks < 2; ++ks)
        pf[ks] = *(const short8*)&Ps[wv][l15 * 64 + (((ks * 4 + quad) ^ (l15 & 7)) << 3)];

      // O += P V
      __builtin_amdgcn_s_setprio(1);
#pragma unroll
      for (int ni = 0; ni < 8; ++ni)
#pragma unroll
        for (int ks = 0; ks < 2; ++ks) {
          int row = ni * 16 + l15;
          short8 vf = *(const short8*)&Vsf[cur][(row * 8 + ((ks * 4 + quad) ^ (row & 7))) * 8];
          oacc[ni] = __builtin_amdgcn_mfma_f32_16x16x32_bf16(pf[ks], vf, oacc[ni], 0, 0, 0);
        }
      __builtin_amdgcn_s_setprio(0);
      __builtin_amdgcn_sched_barrier(0);  // iteration boundary pin
    }

    // epilogue: O / l -> ctx
    float linv = 1.0f / l_s;
    float iv[4];
#pragma unroll
    for (int r = 0; r < 4; ++r) iv[r] = __shfl(linv, quad * 4 + r, 16);
#pragma unroll
    for (int r = 0; r < 4; ++r)
#pragma unroll
      for (int ni = 0; ni < 8; ++ni)
        Ctx[bhq + (size_t)(rowg0 + r) * EMBD + ni * 16 + l15] = f2bf(oacc[ni][r] * iv[r]);
  }
#undef STAGE
}

// ---------------------------------------------------------------------------
extern "C" void kernel_launch(void* const* d_in, const int* in_sizes, int n_in,
                              void* d_out, int out_size, void* d_ws, size_t ws_size,
                              hipStream_t stream)
{
  const float* x  = (const float*)d_in[0];
  // d_in[1] = attn_mask: exactly causal tril(0/-inf) -> applied analytically
  const float* Wq = (const float*)d_in[2];
  const float* bq = (const float*)d_in[3];
  const float* Wk = (const float*)d_in[4];
  const float* bk = (const float*)d_in[5];
  const float* Wv = (const float*)d_in[6];
  const float* bv = (const float*)d_in[7];
  const float* Wo = (const float*)d_in[8];
  const float* bo = (const float*)d_in[9];
  float* out = (float*)d_out;

  const size_t NE = (size_t)BATCH * SEQ * EMBD;  // 16,777,216
  const size_t NW = (size_t)EMBD * EMBD;         //  4,194,304
  short* xb  = (short*)d_ws;
  short* wqb = xb  + NE;
  short* wkb = wqb + NW;
  short* wvb = wkb + NW;
  short* wob = wvb + NW;
  short* q   = wob + NW;
  short* k   = q   + NE;
  short* v   = k   + NE;   // unused scratch (kept for ctx aliasing)
  short* vt  = v   + NE;
  short* ctx = v;   // ctx reuses the v region; total ws = 192 MiB

  // fused conversions: one launch (x is exactly 4*NW elements)
  cvt_all<<<dim3(NW / (256 * 8), 8), 256, 0, stream>>>(
      x, Wq, Wk, Wv, Wo, xb, wqb, wkb, wvb, wob);

  // fused QKV projection: (256 blocks) x 3; y==2 writes Vt directly
  gemm_qkv<<<dim3(256, 3), 512, 0, stream>>>(
      xb, wqb, wkb, wvb, bq, bk, bv, q, k, vt);
  // 512 blocks, 8 waves each: exactly 2 blocks/CU (80 KB LDS), one round
  flash_attn<<<dim3(512), 512, 0, stream>>>(q, k, vt, ctx);
  gemm_out<<<dim3(256), 512, 0, stream>>>(ctx, wob, bo, out);
}